// Round 10
// baseline (1149.141 us; speedup 1.0000x reference)
//
#include <hip/hip_runtime.h>
#include <math.h>

#define MDIM 4096
#define NDIM 4096
#define DDIM 256
#define N_ITER 30

#define TWO_KAPPA 14.426950408889634
#define CLCONST  (-12.0 - TWO_KAPPA)

typedef __attribute__((ext_vector_type(8))) short bf16x8;
typedef __attribute__((ext_vector_type(4))) float f32x4;

__device__ __forceinline__ unsigned encf(float f) {
  unsigned u = __float_as_uint(f);
  return (u & 0x80000000u) ? ~u : (u | 0x80000000u);
}
__device__ __forceinline__ float decf(unsigned u) {
  return __uint_as_float((u & 0x80000000u) ? (u ^ 0x80000000u) : ~u);
}

#define AL_RLX(p)      __hip_atomic_load((p), __ATOMIC_RELAXED, __HIP_MEMORY_SCOPE_AGENT)
#define AADD_RLX(p, v) __hip_atomic_fetch_add((p), (v), __ATOMIC_RELAXED, __HIP_MEMORY_SCOPE_AGENT)
#define AMAX_RLX(p, v) __hip_atomic_fetch_max((p), (v), __ATOMIC_RELAXED, __HIP_MEMORY_SCOPE_AGENT)

// ---------- norms: xx[i], yy[j], Sxx ----------
__global__ void norms_kernel(const float* __restrict__ x, const float* __restrict__ y,
                             float* __restrict__ xx, float* __restrict__ yy,
                             float* __restrict__ Sxx) {
  int wid = threadIdx.x >> 6, lane = threadIdx.x & 63;
  int row = blockIdx.x * 4 + wid;
  const float* src = (row < MDIM) ? x : y;
  int r = (row < MDIM) ? row : row - MDIM;
  const float4* p = (const float4*)(src + (size_t)r * DDIM);
  float4 v = p[lane];
  float s = v.x*v.x + v.y*v.y + v.z*v.z + v.w*v.w;
  #pragma unroll
  for (int off = 32; off; off >>= 1) s += __shfl_down(s, off);
  if (lane == 0) {
    if (row < MDIM) { xx[r] = s; atomicAdd(Sxx, s); }
    else            { yy[r] = s; }
  }
}

// ---------- sx[k] = sum_i x[i,k] ----------
__global__ void sx_kernel(const float* __restrict__ x, float* __restrict__ sx) {
  int tx = threadIdx.x;
  int r0 = blockIdx.x * 16;
  float s = 0.f;
  #pragma unroll
  for (int r = 0; r < 16; ++r) s += x[(size_t)(r0 + r) * DDIM + tx];
  atomicAdd(&sx[tx], s);
}

// ---------- colM[j] = Sxx + MDIM*yy[j] - 2*dot(sx, y_j) ----------
__global__ void colM_kernel(const float* __restrict__ y, const float* __restrict__ sx,
                            const float* __restrict__ yy, const float* __restrict__ Sxx,
                            float* __restrict__ colM) {
  int wid = threadIdx.x >> 6, lane = threadIdx.x & 63;
  int j = blockIdx.x * 4 + wid;
  const float4* py = (const float4*)(y + (size_t)j * DDIM);
  const float4* ps = (const float4*)sx;
  float4 a = py[lane], b = ps[lane];
  float s = a.x*b.x + a.y*b.y + a.z*b.z + a.w*b.w;
  #pragma unroll
  for (int off = 32; off; off >>= 1) s += __shfl_down(s, off);
  if (lane == 0) colM[j] = *Sxx + (float)MDIM * yy[j] - 2.f * s;
}

// ---------- split x,y into bf16 hi/lo pairs ----------
__global__ void split_kernel(const float* __restrict__ x, const float* __restrict__ y,
                             ushort* __restrict__ xh, ushort* __restrict__ xl,
                             ushort* __restrict__ yh, ushort* __restrict__ yl) {
  int g = blockIdx.x * 256 + threadIdx.x;
  int e; const float4* src; ushort* dh; ushort* dl;
  if (g < 262144) { e = g;          src = (const float4*)x; dh = xh; dl = xl; }
  else            { e = g - 262144; src = (const float4*)y; dh = yh; dl = yl; }
  float4 v = src[e];
  float f[4] = {v.x, v.y, v.z, v.w};
  ushort hs[4], ls[4];
  #pragma unroll
  for (int i = 0; i < 4; ++i) {
    unsigned u = __float_as_uint(f[i]);
    unsigned hr = (u + 0x7FFFu + ((u >> 16) & 1u)) >> 16;
    hs[i] = (ushort)hr;
    float hf = __uint_as_float(hr << 16);
    float lo = f[i] - hf;
    unsigned ul = __float_as_uint(lo);
    unsigned lr = (ul + 0x7FFFu + ((ul >> 16) & 1u)) >> 16;
    ls[i] = (ushort)lr;
  }
  *(ushort4*)(dh + (size_t)e * 4) = make_ushort4(hs[0], hs[1], hs[2], hs[3]);
  *(ushort4*)(dl + (size_t)e * 4) = make_ushort4(ls[0], ls[1], ls[2], ls[3]);
}

// ---------- MFMA GEMM: D16 = round(65536 * (xh.yh + xh.yl + xl.yh)), plus maxdot ----------
#define GPAD 56
__global__ __launch_bounds__(256)
void gemm_mfma_kernel(const ushort* __restrict__ xh, const ushort* __restrict__ xl,
                      const ushort* __restrict__ yh, const ushort* __restrict__ yl,
                      short* __restrict__ D16, float* __restrict__ maxdot) {
  __shared__ ushort As[2][128][GPAD];
  __shared__ ushort Bs[2][128][GPAD];
  int tid = threadIdx.x;
  int lane = tid & 63, wid = tid >> 6;
  int bm = blockIdx.x & 31, bn = blockIdx.x >> 5;
  int wrow = (wid >> 1) * 64, wcol = (wid & 1) * 64;
  f32x4 acc[4][4] = {};

  int c0 = tid, c1 = tid + 256;
  int r0 = c0 >> 2, k80 = (c0 & 3) * 8;
  int r1 = c1 >> 2, k81 = (c1 & 3) * 8;
  const size_t arow0 = (size_t)(bm * 128 + r0) * DDIM;
  const size_t arow1 = (size_t)(bm * 128 + r1) * DDIM;
  const size_t brow0 = (size_t)(bn * 128 + r0) * DDIM;
  const size_t brow1 = (size_t)(bn * 128 + r1) * DDIM;

  for (int k0 = 0; k0 < DDIM; k0 += 32) {
    *(uint4*)&As[0][r0][k80] = *(const uint4*)(xh + arow0 + k0 + k80);
    *(uint4*)&As[0][r1][k81] = *(const uint4*)(xh + arow1 + k0 + k81);
    *(uint4*)&As[1][r0][k80] = *(const uint4*)(xl + arow0 + k0 + k80);
    *(uint4*)&As[1][r1][k81] = *(const uint4*)(xl + arow1 + k0 + k81);
    *(uint4*)&Bs[0][r0][k80] = *(const uint4*)(yh + brow0 + k0 + k80);
    *(uint4*)&Bs[0][r1][k81] = *(const uint4*)(yh + brow1 + k0 + k81);
    *(uint4*)&Bs[1][r0][k80] = *(const uint4*)(yl + brow0 + k0 + k80);
    *(uint4*)&Bs[1][r1][k81] = *(const uint4*)(yl + brow1 + k0 + k81);
    __syncthreads();
    int fr = lane & 15, kg = lane >> 4;
    bf16x8 ah[4], al[4], bh[4], bl[4];
    #pragma unroll
    for (int i = 0; i < 4; ++i) {
      ah[i] = *(const bf16x8*)&As[0][wrow + i * 16 + fr][kg * 8];
      al[i] = *(const bf16x8*)&As[1][wrow + i * 16 + fr][kg * 8];
      bh[i] = *(const bf16x8*)&Bs[0][wcol + i * 16 + fr][kg * 8];
      bl[i] = *(const bf16x8*)&Bs[1][wcol + i * 16 + fr][kg * 8];
    }
    #pragma unroll
    for (int i = 0; i < 4; ++i)
      #pragma unroll
      for (int j = 0; j < 4; ++j) {
        acc[i][j] = __builtin_amdgcn_mfma_f32_16x16x32_bf16(ah[i], bh[j], acc[i][j], 0, 0, 0);
        acc[i][j] = __builtin_amdgcn_mfma_f32_16x16x32_bf16(ah[i], bl[j], acc[i][j], 0, 0, 0);
        acc[i][j] = __builtin_amdgcn_mfma_f32_16x16x32_bf16(al[i], bh[j], acc[i][j], 0, 0, 0);
      }
    __syncthreads();
  }
  float tmax = -1.f;
  #pragma unroll
  for (int i = 0; i < 4; ++i) {
    #pragma unroll
    for (int j = 0; j < 4; ++j) {
      int col = bn * 128 + wcol + j * 16 + (lane & 15);
      #pragma unroll
      for (int r = 0; r < 4; ++r) {
        float d = acc[i][j][r];
        tmax = fmaxf(tmax, d);
        int q = __float2int_rn(fminf(fmaxf(d * 65536.f, -32767.f), 32767.f));
        int row = bm * 128 + wrow + i * 16 + (lane >> 4) * 4 + r;
        D16[(size_t)row * NDIM + col] = (short)q;
      }
    }
  }
  __shared__ float sm[4];
  #pragma unroll
  for (int off = 32; off; off >>= 1) tmax = fmaxf(tmax, __shfl_down(tmax, off));
  if (lane == 0) sm[wid] = tmax;
  __syncthreads();
  if (tid == 0) {
    float m = fmaxf(fmaxf(sm[0], sm[1]), fmaxf(sm[2], sm[3]));
    atomicMax((int*)maxdot, __float_as_int(fmaxf(m, 0.f)));
  }
}

// ---------- persistent solver: ONE sync event per iteration ----------
// Block b owns rows [16b,16b+16) (stripe in LDS) and columns [4tid,4tid+4) per
// thread for psi (in registers, computed REDUNDANTLY by every block from the
// 4-group column accumulator colq[t][g][4096], g = b&3).
__global__ __launch_bounds__(1024)
void solve_kernel(const short* __restrict__ D16,
                  float* __restrict__ colq,        // [30][4][4096]
                  const float* __restrict__ maxdot,
                  unsigned* __restrict__ phimaxS,  // [32][16] encf shards
                  unsigned* __restrict__ arrS,     // [32][16] arrival shards
                  unsigned* __restrict__ rootA,    // [32][16] root counters (use [t*16])
                  const float* __restrict__ colM,
                  float* __restrict__ out) {
  __shared__ ushort stripeS[16 * 4096];   // 128 KB
  __shared__ float  redrow[16][16];
  __shared__ float  redm[16];
  __shared__ float  ownS[16];             // phi of owned rows
  __shared__ float  sS[1];                // gathered phimax for next iter
  int tid = threadIdx.x, lane = tid & 63, wid = tid >> 6;
  int b = blockIdx.x;
  int g = b & 3;
  float md = maxdot[0];

  // one-time: stripe -> LDS (coalesced 16B)
  {
    const uint4* src = (const uint4*)(D16 + (size_t)b * 16 * NDIM);
    uint4* dst = (uint4*)stripeS;
    #pragma unroll
    for (int k = 0; k < 8; ++k) dst[tid + 1024 * k] = src[tid + 1024 * k];
  }
  if (tid < 16) ownS[tid] = -6.f;
  float4 psi4 = make_float4(-6.f, -6.f, -6.f, -6.f);
  float phimax = -6.f, psimax = -6.f;
  __syncthreads();

  for (int t = 1; t <= N_ITER; ++t) {
    float sD  = (float)((double)t * (TWO_KAPPA / 65536.0));
    float tCL = (float)((double)t * CLCONST);
    float s2k = (float)((double)t * TWO_KAPPA);
    float tLmax = fmaf(s2k, md, tCL);
    float S  = tLmax + phimax + psimax - 100.f;
    float WS = tCL - S;
    float P0 = psi4.x + WS, P1 = psi4.y + WS, P2 = psi4.z + WS, P3 = psi4.w + WS;

    // ---- E-pass: 16 owned rows x 4 owned cols per thread ----
    float c0 = 0.f, c1 = 0.f, c2 = 0.f, c3 = 0.f;
    float rs[16];
    #pragma unroll
    for (int r = 0; r < 16; ++r) {
      float phr = ownS[r];
      int2 dv = *(const int2*)(stripeS + r * 4096 + 4 * tid);
      float d0 = (float)((short)(dv.x & 0xFFFF));
      float d1 = (float)(dv.x >> 16);
      float d2 = (float)((short)(dv.y & 0xFFFF));
      float d3 = (float)(dv.y >> 16);
      float e0 = exp2f(fmaf(d0, sD, P0 + phr));
      float e1 = exp2f(fmaf(d1, sD, P1 + phr));
      float e2 = exp2f(fmaf(d2, sD, P2 + phr));
      float e3 = exp2f(fmaf(d3, sD, P3 + phr));
      c0 += e0; c1 += e1; c2 += e2; c3 += e3;
      rs[r] = (e0 + e1) + (e2 + e3);
    }
    // ---- group column accumulate (fire-and-forget; overlaps row reduce) ----
    {
      float* cq = colq + ((size_t)(t - 1) * 4 + g) * 4096 + 4 * tid;
      AADD_RLX(cq + 0, c0);
      AADD_RLX(cq + 1, c1);
      AADD_RLX(cq + 2, c2);
      AADD_RLX(cq + 3, c3);
    }
    // ---- row sums -> phi_{t+1} (block-local) + sharded phimax publish ----
    if (t < N_ITER) {
      #pragma unroll
      for (int r = 0; r < 16; ++r) {
        float v = rs[r];
        #pragma unroll
        for (int o = 32; o; o >>= 1) v += __shfl_down(v, o);
        if (lane == 0) redrow[r][wid] = v;
      }
      __syncthreads();
      if (tid < 16) {
        float s = 0.f;
        #pragma unroll
        for (int w = 0; w < 16; ++w) s += redrow[tid][w];
        float pn = ownS[tid] - 0.5f * (S + log2f(fmaxf(s, 1e-30f)));
        ownS[tid] = pn;
        float mx = pn;
        #pragma unroll
        for (int o = 8; o; o >>= 1) mx = fmaxf(mx, __shfl_down(mx, o));
        if (tid == 0) AMAX_RLX(&phimaxS[(t + 1) * 16 + (b & 15)], encf(mx));
      }
    }
    // ---- single arrival (sharded 16x16 -> root) ----
    asm volatile("s_waitcnt vmcnt(0)" ::: "memory");
    __syncthreads();
    if (tid == 0) {
      unsigned old = AADD_RLX(&arrS[t * 16 + (b & 15)], 1u);
      if (old == 15u) AADD_RLX(&rootA[t * 16], 1u);
    }

    if (t < N_ITER) {
      if (tid == 0) {
        while (AL_RLX(&rootA[t * 16]) < 16u) __builtin_amdgcn_s_sleep(4);
        unsigned uf = 0;
        #pragma unroll
        for (int s = 0; s < 16; ++s) {
          unsigned a = AL_RLX(&phimaxS[(t + 1) * 16 + s]);
          uf = a > uf ? a : uf;
        }
        sS[0] = decf(uf);
      }
      __syncthreads();
      // ---- redundant psi_{t+1} for own 4 cols from 4 colq group rows ----
      {
        const float* cr = colq + (size_t)(t - 1) * 4 * 4096;
        float4 q0 = *(const float4*)(cr + 0 * 4096 + 4 * tid);
        float4 q1 = *(const float4*)(cr + 1 * 4096 + 4 * tid);
        float4 q2 = *(const float4*)(cr + 2 * 4096 + 4 * tid);
        float4 q3 = *(const float4*)(cr + 3 * 4096 + 4 * tid);
        float t0 = (q0.x + q1.x) + (q2.x + q3.x);
        float t1 = (q0.y + q1.y) + (q2.y + q3.y);
        float t2 = (q0.z + q1.z) + (q2.z + q3.z);
        float t3 = (q0.w + q1.w) + (q2.w + q3.w);
        psi4.x -= 0.5f * (S + log2f(fmaxf(t0, 1e-30f)));
        psi4.y -= 0.5f * (S + log2f(fmaxf(t1, 1e-30f)));
        psi4.z -= 0.5f * (S + log2f(fmaxf(t2, 1e-30f)));
        psi4.w -= 0.5f * (S + log2f(fmaxf(t3, 1e-30f)));
        float mx = fmaxf(fmaxf(psi4.x, psi4.y), fmaxf(psi4.z, psi4.w));
        #pragma unroll
        for (int o = 32; o; o >>= 1) mx = fmaxf(mx, __shfl_down(mx, o));
        if (lane == 0) redm[wid] = mx;
      }
      __syncthreads();
      {
        float pm = redm[0];
        #pragma unroll
        for (int w = 1; w < 16; ++w) pm = fmaxf(pm, redm[w]);
        psimax = pm;
        phimax = sS[0];
      }
      __syncthreads();   // protect redm/sS before next iteration's writes
    } else {
      // t == N_ITER: only block 0 finishes the loss; others exit.
      if (b == 0) {
        if (tid == 0) {
          while (AL_RLX(&rootA[t * 16]) < 16u) __builtin_amdgcn_s_sleep(4);
        }
        __syncthreads();
        const float* cr = colq + (size_t)(t - 1) * 4 * 4096;
        float4 q0 = *(const float4*)(cr + 0 * 4096 + 4 * tid);
        float4 q1 = *(const float4*)(cr + 1 * 4096 + 4 * tid);
        float4 q2 = *(const float4*)(cr + 2 * 4096 + 4 * tid);
        float4 q3 = *(const float4*)(cr + 3 * 4096 + 4 * tid);
        float4 mv = *(const float4*)(colM + 4 * tid);
        const float sc = 9.094947017729282e-13f;   // 2^-40 prescale
        float term = ((q0.x + q1.x) + (q2.x + q3.x)) * sc * mv.x
                   + ((q0.y + q1.y) + (q2.y + q3.y)) * sc * mv.y
                   + ((q0.z + q1.z) + (q2.z + q3.z)) * sc * mv.z
                   + ((q0.w + q1.w) + (q2.w + q3.w)) * sc * mv.w;
        #pragma unroll
        for (int o = 32; o; o >>= 1) term += __shfl_down(term, o);
        if (lane == 0) redm[wid] = term;
        __syncthreads();
        if (tid == 0) {
          float tot = 0.f;
          #pragma unroll
          for (int w = 0; w < 16; ++w) tot += redm[w];
          out[0] = exp2f(log2f(tot) + S + 16.f);   // +40 (prescale) - 24 (1/m^2)
        }
      }
    }
  }
}

extern "C" void kernel_launch(void* const* d_in, const int* in_sizes, int n_in,
                              void* d_out, int out_size, void* d_ws, size_t ws_size,
                              hipStream_t stream) {
  const float* x = (const float*)d_in[0];
  const float* y = (const float*)d_in[1];
  float* out = (float*)d_out;

  char* ws = (char*)d_ws;
  size_t off = 0;
  auto alloc = [&](size_t bytes) -> void* {
    void* p = ws + off;
    off += (bytes + 255) & ~(size_t)255;
    return p;
  };
  short*    D16     = (short*)alloc((size_t)MDIM * NDIM * 2);      // 32 MB
  float*    colq    = (float*)alloc((size_t)N_ITER * 4 * NDIM * 4); // ~2 MB
  ushort*   xh      = (ushort*)alloc((size_t)MDIM * DDIM * 2);
  ushort*   xl      = (ushort*)alloc((size_t)MDIM * DDIM * 2);
  ushort*   yh      = (ushort*)alloc((size_t)NDIM * DDIM * 2);
  ushort*   yl      = (ushort*)alloc((size_t)NDIM * DDIM * 2);
  float*    xx      = (float*)alloc(MDIM * 4);
  float*    yy      = (float*)alloc(NDIM * 4);
  float*    sx      = (float*)alloc(DDIM * 4);
  float*    colM    = (float*)alloc(NDIM * 4);
  float*    Sxx     = (float*)alloc(4);
  float*    maxd    = (float*)alloc(4);
  unsigned* phimaxS = (unsigned*)alloc(32 * 16 * 4);
  unsigned* arrS    = (unsigned*)alloc(32 * 16 * 4);
  unsigned* rootA   = (unsigned*)alloc(32 * 16 * 4);

  hipMemsetAsync(Sxx, 0, 4, stream);
  hipMemsetAsync(maxd, 0, 4, stream);
  hipMemsetAsync(sx, 0, DDIM * 4, stream);
  hipMemsetAsync(colq, 0, (size_t)N_ITER * 4 * NDIM * 4, stream);
  hipMemsetAsync(phimaxS, 0, 32 * 16 * 4, stream);
  hipMemsetAsync(arrS, 0, 32 * 16 * 4, stream);
  hipMemsetAsync(rootA, 0, 32 * 16 * 4, stream);

  norms_kernel<<<2048, 256, 0, stream>>>(x, y, xx, yy, Sxx);
  sx_kernel<<<256, 256, 0, stream>>>(x, sx);
  colM_kernel<<<1024, 256, 0, stream>>>(y, sx, yy, Sxx, colM);
  split_kernel<<<2048, 256, 0, stream>>>(x, y, xh, xl, yh, yl);
  gemm_mfma_kernel<<<1024, 256, 0, stream>>>(xh, xl, yh, yl, D16, maxd);

  void* kargs[] = {(void*)&D16, (void*)&colq, (void*)&maxd,
                   (void*)&phimaxS, (void*)&arrS, (void*)&rootA,
                   (void*)&colM, (void*)&out};
  hipLaunchCooperativeKernel((void*)solve_kernel, dim3(256), dim3(1024),
                             kargs, 0, stream);
}

// Round 12
// 1062.745 us; speedup vs baseline: 1.0813x; 1.0813x over previous
//
#include <hip/hip_runtime.h>
#include <math.h>

#define MDIM 4096
#define NDIM 4096
#define DDIM 256
#define N_ITER 30

#define TWO_KAPPA 14.426950408889634
#define CLCONST  (-12.0 - TWO_KAPPA)

typedef __attribute__((ext_vector_type(8))) short bf16x8;
typedef __attribute__((ext_vector_type(4))) float f32x4;
typedef unsigned long long ull;

__device__ __forceinline__ unsigned encf(float f) {
  unsigned u = __float_as_uint(f);
  return (u & 0x80000000u) ? ~u : (u | 0x80000000u);
}
__device__ __forceinline__ float decf(unsigned u) {
  return __uint_as_float((u & 0x80000000u) ? (u ^ 0x80000000u) : ~u);
}

#define AL_RLX(p)      __hip_atomic_load((p), __ATOMIC_RELAXED, __HIP_MEMORY_SCOPE_AGENT)
#define AS_RLX(p, v)   __hip_atomic_store((p), (v), __ATOMIC_RELAXED, __HIP_MEMORY_SCOPE_AGENT)
#define AADD_RLX(p, v) __hip_atomic_fetch_add((p), (v), __ATOMIC_RELAXED, __HIP_MEMORY_SCOPE_AGENT)
#define AMAX_RLX(p, v) __hip_atomic_fetch_max((p), (v), __ATOMIC_RELAXED, __HIP_MEMORY_SCOPE_AGENT)

// ---------- norms: xx[i], yy[j], Sxx ----------
__global__ void norms_kernel(const float* __restrict__ x, const float* __restrict__ y,
                             float* __restrict__ xx, float* __restrict__ yy,
                             float* __restrict__ Sxx) {
  int wid = threadIdx.x >> 6, lane = threadIdx.x & 63;
  int row = blockIdx.x * 4 + wid;
  const float* src = (row < MDIM) ? x : y;
  int r = (row < MDIM) ? row : row - MDIM;
  const float4* p = (const float4*)(src + (size_t)r * DDIM);
  float4 v = p[lane];
  float s = v.x*v.x + v.y*v.y + v.z*v.z + v.w*v.w;
  #pragma unroll
  for (int off = 32; off; off >>= 1) s += __shfl_down(s, off);
  if (lane == 0) {
    if (row < MDIM) { xx[r] = s; atomicAdd(Sxx, s); }
    else            { yy[r] = s; }
  }
}

// ---------- sx[k] = sum_i x[i,k] ----------
__global__ void sx_kernel(const float* __restrict__ x, float* __restrict__ sx) {
  int tx = threadIdx.x;
  int r0 = blockIdx.x * 16;
  float s = 0.f;
  #pragma unroll
  for (int r = 0; r < 16; ++r) s += x[(size_t)(r0 + r) * DDIM + tx];
  atomicAdd(&sx[tx], s);
}

// ---------- colM[j] = Sxx + MDIM*yy[j] - 2*dot(sx, y_j) ----------
__global__ void colM_kernel(const float* __restrict__ y, const float* __restrict__ sx,
                            const float* __restrict__ yy, const float* __restrict__ Sxx,
                            float* __restrict__ colM) {
  int wid = threadIdx.x >> 6, lane = threadIdx.x & 63;
  int j = blockIdx.x * 4 + wid;
  const float4* py = (const float4*)(y + (size_t)j * DDIM);
  const float4* ps = (const float4*)sx;
  float4 a = py[lane], b = ps[lane];
  float s = a.x*b.x + a.y*b.y + a.z*b.z + a.w*b.w;
  #pragma unroll
  for (int off = 32; off; off >>= 1) s += __shfl_down(s, off);
  if (lane == 0) colM[j] = *Sxx + (float)MDIM * yy[j] - 2.f * s;
}

// ---------- split x,y into bf16 hi/lo pairs ----------
__global__ void split_kernel(const float* __restrict__ x, const float* __restrict__ y,
                             ushort* __restrict__ xh, ushort* __restrict__ xl,
                             ushort* __restrict__ yh, ushort* __restrict__ yl) {
  int g = blockIdx.x * 256 + threadIdx.x;
  int e; const float4* src; ushort* dh; ushort* dl;
  if (g < 262144) { e = g;          src = (const float4*)x; dh = xh; dl = xl; }
  else            { e = g - 262144; src = (const float4*)y; dh = yh; dl = yl; }
  float4 v = src[e];
  float f[4] = {v.x, v.y, v.z, v.w};
  ushort hs[4], ls[4];
  #pragma unroll
  for (int i = 0; i < 4; ++i) {
    unsigned u = __float_as_uint(f[i]);
    unsigned hr = (u + 0x7FFFu + ((u >> 16) & 1u)) >> 16;
    hs[i] = (ushort)hr;
    float hf = __uint_as_float(hr << 16);
    float lo = f[i] - hf;
    unsigned ul = __float_as_uint(lo);
    unsigned lr = (ul + 0x7FFFu + ((ul >> 16) & 1u)) >> 16;
    ls[i] = (ushort)lr;
  }
  *(ushort4*)(dh + (size_t)e * 4) = make_ushort4(hs[0], hs[1], hs[2], hs[3]);
  *(ushort4*)(dl + (size_t)e * 4) = make_ushort4(ls[0], ls[1], ls[2], ls[3]);
}

// ---------- MFMA GEMM: D16 = round(65536 * (xh.yh + xh.yl + xl.yh)), plus maxdot ----------
#define GPAD 56
__global__ __launch_bounds__(256)
void gemm_mfma_kernel(const ushort* __restrict__ xh, const ushort* __restrict__ xl,
                      const ushort* __restrict__ yh, const ushort* __restrict__ yl,
                      short* __restrict__ D16, float* __restrict__ maxdot) {
  __shared__ ushort As[2][128][GPAD];
  __shared__ ushort Bs[2][128][GPAD];
  int tid = threadIdx.x;
  int lane = tid & 63, wid = tid >> 6;
  int bm = blockIdx.x & 31, bn = blockIdx.x >> 5;
  int wrow = (wid >> 1) * 64, wcol = (wid & 1) * 64;
  f32x4 acc[4][4] = {};

  int c0 = tid, c1 = tid + 256;
  int r0 = c0 >> 2, k80 = (c0 & 3) * 8;
  int r1 = c1 >> 2, k81 = (c1 & 3) * 8;
  const size_t arow0 = (size_t)(bm * 128 + r0) * DDIM;
  const size_t arow1 = (size_t)(bm * 128 + r1) * DDIM;
  const size_t brow0 = (size_t)(bn * 128 + r0) * DDIM;
  const size_t brow1 = (size_t)(bn * 128 + r1) * DDIM;

  for (int k0 = 0; k0 < DDIM; k0 += 32) {
    *(uint4*)&As[0][r0][k80] = *(const uint4*)(xh + arow0 + k0 + k80);
    *(uint4*)&As[0][r1][k81] = *(const uint4*)(xh + arow1 + k0 + k81);
    *(uint4*)&As[1][r0][k80] = *(const uint4*)(xl + arow0 + k0 + k80);
    *(uint4*)&As[1][r1][k81] = *(const uint4*)(xl + arow1 + k0 + k81);
    *(uint4*)&Bs[0][r0][k80] = *(const uint4*)(yh + brow0 + k0 + k80);
    *(uint4*)&Bs[0][r1][k81] = *(const uint4*)(yh + brow1 + k0 + k81);
    *(uint4*)&Bs[1][r0][k80] = *(const uint4*)(yl + brow0 + k0 + k80);
    *(uint4*)&Bs[1][r1][k81] = *(const uint4*)(yl + brow1 + k0 + k81);
    __syncthreads();
    int fr = lane & 15, kg = lane >> 4;
    bf16x8 ah[4], al[4], bh[4], bl[4];
    #pragma unroll
    for (int i = 0; i < 4; ++i) {
      ah[i] = *(const bf16x8*)&As[0][wrow + i * 16 + fr][kg * 8];
      al[i] = *(const bf16x8*)&As[1][wrow + i * 16 + fr][kg * 8];
      bh[i] = *(const bf16x8*)&Bs[0][wcol + i * 16 + fr][kg * 8];
      bl[i] = *(const bf16x8*)&Bs[1][wcol + i * 16 + fr][kg * 8];
    }
    #pragma unroll
    for (int i = 0; i < 4; ++i)
      #pragma unroll
      for (int j = 0; j < 4; ++j) {
        acc[i][j] = __builtin_amdgcn_mfma_f32_16x16x32_bf16(ah[i], bh[j], acc[i][j], 0, 0, 0);
        acc[i][j] = __builtin_amdgcn_mfma_f32_16x16x32_bf16(ah[i], bl[j], acc[i][j], 0, 0, 0);
        acc[i][j] = __builtin_amdgcn_mfma_f32_16x16x32_bf16(al[i], bh[j], acc[i][j], 0, 0, 0);
      }
    __syncthreads();
  }
  float tmax = -1.f;
  #pragma unroll
  for (int i = 0; i < 4; ++i) {
    #pragma unroll
    for (int j = 0; j < 4; ++j) {
      int col = bn * 128 + wcol + j * 16 + (lane & 15);
      #pragma unroll
      for (int r = 0; r < 4; ++r) {
        float d = acc[i][j][r];
        tmax = fmaxf(tmax, d);
        int q = __float2int_rn(fminf(fmaxf(d * 65536.f, -32767.f), 32767.f));
        int row = bm * 128 + wrow + i * 16 + (lane >> 4) * 4 + r;
        D16[(size_t)row * NDIM + col] = (short)q;
      }
    }
  }
  __shared__ float sm[4];
  #pragma unroll
  for (int off = 32; off; off >>= 1) tmax = fmaxf(tmax, __shfl_down(tmax, off));
  if (lane == 0) sm[wid] = tmax;
  __syncthreads();
  if (tid == 0) {
    float m = fmaxf(fmaxf(sm[0], sm[1]), fmaxf(sm[2], sm[3]));
    atomicMax((int*)maxdot, __float_as_int(fmaxf(m, 0.f)));
  }
}

// ---------- 2D-tiled persistent solver: 16x16 blocks of 256x256 tiles ----------
// Worker role: block b=(R,C) holds tile rows 256R.., cols 256C.. in LDS; E-pass
// produces row partials rp[C][4096] and col partials cp[R][4096] (~2 KB/block).
// Reducer role: block b reduces rows & cols [16b,16b+16): phi/psi updates + maxes.
// Two sharded arrivals per iteration. Formulas identical to r9/r10 (validated).
__global__ __launch_bounds__(1024)
void solve_kernel(const short* __restrict__ D16,
                  float* __restrict__ rp, float* __restrict__ cp,      // [16][4096] each
                  float* __restrict__ pubPhi, float* __restrict__ pubPsi,
                  const float* __restrict__ maxdot,
                  unsigned* __restrict__ phimaxS, unsigned* __restrict__ psimaxS,
                  unsigned* __restrict__ arrA, unsigned* __restrict__ rootA,
                  unsigned* __restrict__ arrB, unsigned* __restrict__ rootB,
                  const float* __restrict__ colM,
                  float* __restrict__ lossacc, unsigned* __restrict__ lossdone,
                  float* __restrict__ out) {
  __shared__ ushort tileS[256 * 256];   // 128 KB
  __shared__ float  cpS[16][256];       // 16 KB
  __shared__ float  phiS[256], psiS[256];
  __shared__ float  sS[2];
  int tid = threadIdx.x, lane = tid & 63;
  int b = blockIdx.x;
  int R = b >> 4, C = b & 15;
  int rg = tid >> 6, c4 = tid & 63;
  float md = maxdot[0];

  // one-time tile load (rows 256R..256R+255, cols 256C..256C+255)
  {
    int row = tid >> 2, chunk = tid & 3;
    const ushort* src = (const ushort*)D16 + (size_t)(256 * R + row) * NDIM + 256 * C + 64 * chunk;
    ushort* dst = tileS + row * 256 + 64 * chunk;
    #pragma unroll
    for (int q = 0; q < 8; ++q)
      *(uint4*)(dst + 8 * q) = *(const uint4*)(src + 8 * q);
  }
  float ownPhi = -6.f, ownPsi = -6.f;   // reducer state (tid<16)
  float phimax = -6.f, psimax = -6.f;
  if (tid < 256) { phiS[tid] = -6.f; psiS[tid] = -6.f; }
  __syncthreads();

  float S = 0.f;
  for (int t = 1; t <= N_ITER; ++t) {
    float sD  = (float)((double)t * (TWO_KAPPA / 65536.0));
    float tCL = (float)((double)t * CLCONST);
    float s2k = (float)((double)t * TWO_KAPPA);
    float tLmax = fmaf(s2k, md, tCL);
    S = tLmax + phimax + psimax - 100.f;
    float WS = tCL - S;

    float P0 = psiS[c4 * 4 + 0] + WS;
    float P1 = psiS[c4 * 4 + 1] + WS;
    float P2 = psiS[c4 * 4 + 2] + WS;
    float P3 = psiS[c4 * 4 + 3] + WS;

    // ---- E-pass: 16 rows x 4 cols per thread ----
    float ca0 = 0.f, ca1 = 0.f, ca2 = 0.f, ca3 = 0.f;
    float rs[16];
    #pragma unroll
    for (int r = 0; r < 16; ++r) {
      float phr = phiS[rg * 16 + r];
      int2 dv = *(const int2*)(tileS + (rg * 16 + r) * 256 + c4 * 4);
      float d0 = (float)((short)(dv.x & 0xFFFF));
      float d1 = (float)(dv.x >> 16);
      float d2 = (float)((short)(dv.y & 0xFFFF));
      float d3 = (float)(dv.y >> 16);
      float e0 = exp2f(fmaf(d0, sD, P0 + phr));
      float e1 = exp2f(fmaf(d1, sD, P1 + phr));
      float e2 = exp2f(fmaf(d2, sD, P2 + phr));
      float e3 = exp2f(fmaf(d3, sD, P3 + phr));
      ca0 += e0; ca1 += e1; ca2 += e2; ca3 += e3;
      rs[r] = (e0 + e1) + (e2 + e3);
    }
    // ---- row partials: wave-reduce (64 lanes = this wave's 256 cols), publish ----
    if (t < N_ITER) {
      #pragma unroll
      for (int r = 0; r < 16; ++r) {
        float v = rs[r];
        #pragma unroll
        for (int o = 32; o; o >>= 1) v += __shfl_down(v, o);
        if (lane == 0) AS_RLX(&rp[C * 4096 + 256 * R + rg * 16 + r], v);
      }
    }
    // ---- col partials via LDS ----
    cpS[rg][c4 * 4 + 0] = ca0; cpS[rg][c4 * 4 + 1] = ca1;
    cpS[rg][c4 * 4 + 2] = ca2; cpS[rg][c4 * 4 + 3] = ca3;
    __syncthreads();
    if (tid < 256) {
      float tot = 0.f;
      #pragma unroll
      for (int g2 = 0; g2 < 16; ++g2) tot += cpS[g2][tid];
      AS_RLX(&cp[R * 4096 + 256 * C + tid], tot);
    }
    asm volatile("s_waitcnt vmcnt(0)" ::: "memory");
    __syncthreads();
    // ---- arrival A (sharded 16x16 -> root) ----
    if (tid == 0) {
      unsigned old = AADD_RLX(&arrA[t * 16 + (b & 15)], 1u);
      if (old == 15u) AADD_RLX(&rootA[t * 16], 1u);
      while (AL_RLX(&rootA[t * 16]) < 16u) __builtin_amdgcn_s_sleep(2);
    }
    __syncthreads();

    if (t < N_ITER) {
      // ---- reducer: rows & cols [16b, 16b+16) ----
      if (tid < 16) {
        float s1 = 0.f, s2 = 0.f;
        #pragma unroll
        for (int k = 0; k < 16; ++k) {
          s1 += AL_RLX(&rp[k * 4096 + 16 * b + tid]);
          s2 += AL_RLX(&cp[k * 4096 + 16 * b + tid]);
        }
        float pnf = ownPhi - 0.5f * (S + log2f(fmaxf(s1, 1e-30f)));
        float pns = ownPsi - 0.5f * (S + log2f(fmaxf(s2, 1e-30f)));
        ownPhi = pnf; ownPsi = pns;
        AS_RLX(&pubPhi[16 * b + tid], pnf);
        AS_RLX(&pubPsi[16 * b + tid], pns);
        float mf = pnf, ms = pns;
        #pragma unroll
        for (int o = 8; o; o >>= 1) {
          mf = fmaxf(mf, __shfl_down(mf, o));
          ms = fmaxf(ms, __shfl_down(ms, o));
        }
        if (tid == 0) {
          AMAX_RLX(&phimaxS[(t + 1) * 16 + (b & 15)], encf(mf));
          AMAX_RLX(&psimaxS[(t + 1) * 16 + (b & 15)], encf(ms));
        }
      }
      // ---- arrival B + max gather ----
      if (tid == 0) {
        asm volatile("s_waitcnt vmcnt(0)" ::: "memory");
        unsigned old = AADD_RLX(&arrB[t * 16 + (b & 15)], 1u);
        if (old == 15u) AADD_RLX(&rootB[t * 16], 1u);
        while (AL_RLX(&rootB[t * 16]) < 16u) __builtin_amdgcn_s_sleep(2);
        unsigned uf = 0, up = 0;
        #pragma unroll
        for (int s = 0; s < 16; ++s) {
          unsigned a  = AL_RLX(&phimaxS[(t + 1) * 16 + s]); uf = a  > uf ? a  : uf;
          unsigned c2 = AL_RLX(&psimaxS[(t + 1) * 16 + s]); up = c2 > up ? c2 : up;
        }
        sS[0] = decf(uf); sS[1] = decf(up);
      }
      __syncthreads();
      phimax = sS[0]; psimax = sS[1];
      // ---- load next phi/psi slices (2 KB, uncached) ----
      if (tid < 128) {
        ull a = AL_RLX((const ull*)&pubPhi[256 * R + 2 * tid]);
        phiS[2 * tid]     = __uint_as_float((unsigned)a);
        phiS[2 * tid + 1] = __uint_as_float((unsigned)(a >> 32));
        ull c2 = AL_RLX((const ull*)&pubPsi[256 * C + 2 * tid]);
        psiS[2 * tid]     = __uint_as_float((unsigned)c2);
        psiS[2 * tid + 1] = __uint_as_float((unsigned)(c2 >> 32));
      }
      __syncthreads();
    } else {
      // ---- t == 30: loss from colsums of owned cols ----
      if (tid < 16) {
        float s2 = 0.f;
        #pragma unroll
        for (int k = 0; k < 16; ++k) s2 += AL_RLX(&cp[k * 4096 + 16 * b + tid]);
        float term = (s2 * 9.094947017729282e-13f) * colM[16 * b + tid];  // 2^-40 prescale
        #pragma unroll
        for (int o = 8; o; o >>= 1) term += __shfl_down(term, o);
        if (tid == 0) {
          AADD_RLX(&lossacc[b & 15], term);
          asm volatile("s_waitcnt vmcnt(0)" ::: "memory");
          AADD_RLX(lossdone, 1u);
          if (b == 0) {
            while (AL_RLX(lossdone) < 256u) __builtin_amdgcn_s_sleep(2);
            float tt = 0.f;
            #pragma unroll
            for (int s = 0; s < 16; ++s) tt += AL_RLX(&lossacc[s]);
            out[0] = exp2f(log2f(tt) + S + 16.f);   // +40 (prescale) - 24 (1/m^2)
          }
        }
      }
    }
  }
}

extern "C" void kernel_launch(void* const* d_in, const int* in_sizes, int n_in,
                              void* d_out, int out_size, void* d_ws, size_t ws_size,
                              hipStream_t stream) {
  const float* x = (const float*)d_in[0];
  const float* y = (const float*)d_in[1];
  float* out = (float*)d_out;

  char* ws = (char*)d_ws;
  size_t off = 0;
  auto alloc = [&](size_t bytes) -> void* {
    void* p = ws + off;
    off += (bytes + 255) & ~(size_t)255;
    return p;
  };
  short*    D16     = (short*)alloc((size_t)MDIM * NDIM * 2);      // 32 MB
  float*    rp      = (float*)alloc((size_t)16 * NDIM * 4);        // 256 KB
  float*    cp      = (float*)alloc((size_t)16 * NDIM * 4);        // 256 KB
  ushort*   xh      = (ushort*)alloc((size_t)MDIM * DDIM * 2);
  ushort*   xl      = (ushort*)alloc((size_t)MDIM * DDIM * 2);
  ushort*   yh      = (ushort*)alloc((size_t)NDIM * DDIM * 2);
  ushort*   yl      = (ushort*)alloc((size_t)NDIM * DDIM * 2);
  float*    xx      = (float*)alloc(MDIM * 4);
  float*    yy      = (float*)alloc(NDIM * 4);
  float*    sx      = (float*)alloc(DDIM * 4);
  float*    colM    = (float*)alloc(NDIM * 4);
  float*    Sxx     = (float*)alloc(4);
  float*    maxd    = (float*)alloc(4);
  float*    pubPhi  = (float*)alloc(MDIM * 4);
  float*    pubPsi  = (float*)alloc(NDIM * 4);
  unsigned* phimaxS = (unsigned*)alloc(32 * 16 * 4);
  unsigned* psimaxS = (unsigned*)alloc(32 * 16 * 4);
  unsigned* arrA    = (unsigned*)alloc(32 * 16 * 4);
  unsigned* rootA   = (unsigned*)alloc(32 * 16 * 4);
  unsigned* arrB    = (unsigned*)alloc(32 * 16 * 4);
  unsigned* rootB   = (unsigned*)alloc(32 * 16 * 4);
  float*    lossacc = (float*)alloc(16 * 4);
  unsigned* lossdone= (unsigned*)alloc(16 * 4);

  hipMemsetAsync(Sxx, 0, 4, stream);
  hipMemsetAsync(maxd, 0, 4, stream);
  hipMemsetAsync(sx, 0, DDIM * 4, stream);
  hipMemsetAsync(phimaxS, 0, 32 * 16 * 4, stream);
  hipMemsetAsync(psimaxS, 0, 32 * 16 * 4, stream);
  hipMemsetAsync(arrA, 0, 32 * 16 * 4, stream);
  hipMemsetAsync(rootA, 0, 32 * 16 * 4, stream);
  hipMemsetAsync(arrB, 0, 32 * 16 * 4, stream);
  hipMemsetAsync(rootB, 0, 32 * 16 * 4, stream);
  hipMemsetAsync(lossacc, 0, 16 * 4, stream);
  hipMemsetAsync(lossdone, 0, 16 * 4, stream);

  norms_kernel<<<2048, 256, 0, stream>>>(x, y, xx, yy, Sxx);
  sx_kernel<<<256, 256, 0, stream>>>(x, sx);
  colM_kernel<<<1024, 256, 0, stream>>>(y, sx, yy, Sxx, colM);
  split_kernel<<<2048, 256, 0, stream>>>(x, y, xh, xl, yh, yl);
  gemm_mfma_kernel<<<1024, 256, 0, stream>>>(xh, xl, yh, yl, D16, maxd);

  void* kargs[] = {(void*)&D16, (void*)&rp, (void*)&cp,
                   (void*)&pubPhi, (void*)&pubPsi, (void*)&maxd,
                   (void*)&phimaxS, (void*)&psimaxS,
                   (void*)&arrA, (void*)&rootA, (void*)&arrB, (void*)&rootB,
                   (void*)&colM, (void*)&lossacc, (void*)&lossdone, (void*)&out};
  hipLaunchCooperativeKernel((void*)solve_kernel, dim3(256), dim3(1024),
                             kargs, 0, stream);
}